// Round 5
// baseline (1600.987 us; speedup 1.0000x reference)
//
#include <hip/hip_runtime.h>
#include <hip/hip_bf16.h>
#include <cmath>

// ---------------------------------------------------------------------------
// BeliefTransformerBlock: LN1 -> QKV -> masked attention -> LN2 -> FC+GELU -> proj
// B=32, N=1024, D=512.
//
// R5: gemm256 restructured for 2 blocks/CU: 2-slot LDS ring (64 KiB),
// vmcnt(0)+barrier per K-step (trivially race-free), stage(t+1) issued
// BEFORE compute(t) so loads fly under MFMA; inter-block overlap covers the
// drains (m97/m114 mechanism — my 1-block/CU pipelines serialized on them).
// Compile-time K-tile count (KT template) for all fixed-K launches.
// transpose_cast + LN1 fused into one prep launch (8 dispatches total).
//
// d_ws layout (floor 100 MiB):
//   0  wqkvT/wfcT/wprojT (4 MiB)
//   4  qk [b][n][1024] q|k (64 MiB)   -> after scores: y @4 (32), ln2o @36 (32)
//   68 vT [b][d][n] (32 MiB)          -> after attnV: gelub @68 (32)
// d_out (64 MiB): h/scoresAll scratch, finally fp32 out.
// ---------------------------------------------------------------------------

using f16 = _Float16;
typedef _Float16 f16x8 __attribute__((ext_vector_type(8)));
typedef _Float16 f16x4 __attribute__((ext_vector_type(4)));
typedef _Float16 f16x2 __attribute__((ext_vector_type(2)));
typedef float f32x4 __attribute__((ext_vector_type(4)));

#define NB 32
#define NN 1024
#define ND 512

#define GLOAD_LDS16(g, l)                                                     \
    __builtin_amdgcn_global_load_lds(                                         \
        (const __attribute__((address_space(1))) void*)(g),                   \
        (__attribute__((address_space(3))) void*)(l), 16, 0, 0)

// ---------------------------------------------------------------------------
// LN row body (fp32 input), wave-per-row: no LDS, no barriers.
// ---------------------------------------------------------------------------
__device__ __forceinline__ void ln_row_f32(const float* __restrict__ xrow,
                                           const float* __restrict__ gamma,
                                           f16* __restrict__ orow, int lane) {
    float v[8], g[8];
    const float4* p = (const float4*)xrow;
    const float4 a = p[lane], b = p[lane + 64];
    v[0] = a.x; v[1] = a.y; v[2] = a.z; v[3] = a.w;
    v[4] = b.x; v[5] = b.y; v[6] = b.z; v[7] = b.w;
    const float4* gp = (const float4*)gamma;
    const float4 ga = gp[lane], gb = gp[lane + 64];
    g[0] = ga.x; g[1] = ga.y; g[2] = ga.z; g[3] = ga.w;
    g[4] = gb.x; g[5] = gb.y; g[6] = gb.z; g[7] = gb.w;

    float s = 0.f;
#pragma unroll
    for (int e = 0; e < 8; e++) s += v[e];
#pragma unroll
    for (int o = 32; o > 0; o >>= 1) s += __shfl_xor(s, o, 64);
    const float mean = s * (1.f / 512.f);

    float q = 0.f;
#pragma unroll
    for (int e = 0; e < 8; e++) {
        v[e] -= mean;
        q += v[e] * v[e];
    }
#pragma unroll
    for (int o = 32; o > 0; o >>= 1) q += __shfl_xor(q, o, 64);
    const float rstd = rsqrtf(q * (1.f / 512.f) + 1e-5f);

    f16x4 o0, o1;
#pragma unroll
    for (int e = 0; e < 4; e++) {
        o0[e] = (f16)(v[e] * rstd * g[e]);
        o1[e] = (f16)(v[4 + e] * rstd * g[4 + e]);
    }
    ((f16x4*)orow)[lane] = o0;
    ((f16x4*)orow)[lane + 64] = o1;
}

// ---------------------------------------------------------------------------
// Fused prep: blocks [0,2304) transpose+cast the 3 weights; blocks
// [2304,10496) do LN1 (4 rows each, wave per row). One launch, 256 thr.
// ---------------------------------------------------------------------------
__global__ __launch_bounds__(256) void prep_fused(
    const float* __restrict__ wqkv, f16* __restrict__ wqkvT,
    const float* __restrict__ wfc, f16* __restrict__ wfcT,
    const float* __restrict__ wproj, f16* __restrict__ wprojT,
    const float* __restrict__ x, const float* __restrict__ g1,
    f16* __restrict__ h) {
    const int bid = blockIdx.x;
    const int tid = threadIdx.x;
    if (bid < 2304) {
        const int z = bid / 768, rem = bid % 768;
        const int bx = rem % 48, by = rem / 48;
        const float* w = (z == 0) ? wqkv : (z == 1) ? wfc : wproj;
        f16* wT       = (z == 0) ? wqkvT : (z == 1) ? wfcT : wprojT;
        const int Ncols = (z == 0) ? 1536 : 512;
        if (bx * 32 >= Ncols) return;
        __shared__ float tile[32][33];
        const int n0 = bx * 32, k0 = by * 32;
        const int tx = tid & 31, ty = tid >> 5;
        for (int i = ty; i < 32; i += 8)
            tile[i][tx] = w[(long long)(k0 + i) * Ncols + n0 + tx];
        __syncthreads();
        for (int i = ty; i < 32; i += 8)
            wT[(long long)(n0 + i) * 512 + k0 + tx] = (f16)tile[tx][i];
    } else {
        const int wave = tid >> 6, lane = tid & 63;
        const long long row = (long long)(bid - 2304) * 4 + wave;
        ln_row_f32(x + row * ND, g1, h + row * ND, lane);
    }
}

// ---------------------------------------------------------------------------
// LayerNorm (f16 input), wave-per-row, 4 rows per block. Used for LN2.
// ---------------------------------------------------------------------------
__global__ __launch_bounds__(256) void ln_wave_h(const f16* __restrict__ x,
                                                 const float* __restrict__ gamma,
                                                 f16* __restrict__ out) {
    const int wave = threadIdx.x >> 6, lane = threadIdx.x & 63;
    const long long base = ((long long)blockIdx.x * 4 + wave) * ND;

    float v[8], g[8];
    const f16x8 t = ((const f16x8*)(x + base))[lane];
#pragma unroll
    for (int e = 0; e < 8; e++) v[e] = (float)t[e];
    const float4* gp = (const float4*)gamma;
    const float4 ga = gp[2 * lane], gb = gp[2 * lane + 1];
    g[0] = ga.x; g[1] = ga.y; g[2] = ga.z; g[3] = ga.w;
    g[4] = gb.x; g[5] = gb.y; g[6] = gb.z; g[7] = gb.w;

    float s = 0.f;
#pragma unroll
    for (int e = 0; e < 8; e++) s += v[e];
#pragma unroll
    for (int o = 32; o > 0; o >>= 1) s += __shfl_xor(s, o, 64);
    const float mean = s * (1.f / 512.f);

    float q = 0.f;
#pragma unroll
    for (int e = 0; e < 8; e++) {
        v[e] -= mean;
        q += v[e] * v[e];
    }
#pragma unroll
    for (int o = 32; o > 0; o >>= 1) q += __shfl_xor(q, o, 64);
    const float rstd = rsqrtf(q * (1.f / 512.f) + 1e-5f);

    f16x8 o8;
#pragma unroll
    for (int e = 0; e < 8; e++) o8[e] = (f16)(v[e] * rstd * g[e]);
    ((f16x8*)(out + base))[lane] = o8;
}

// ---------------------------------------------------------------------------
// Masked softmax, fp16 in-place, one WAVE per row (no LDS, no barriers).
// Loads AND stores only c < round64(sz) (attn@V's K bound; zero-filled tail).
// ---------------------------------------------------------------------------
__global__ __launch_bounds__(256) void softmax_wave(f16* __restrict__ scores,
                                                    const int* __restrict__ sizes) {
    const int b = blockIdx.y;
    const int wave = threadIdx.x >> 6, lane = threadIdx.x & 63;
    const int row = blockIdx.x * 4 + wave;
    f16* srow = scores + ((long long)b * NN + row) * NN;
    const int sz = sizes[b];
    const int keff = (sz + 63) & ~63;
    const int cbase = lane * 16;

    float v[16];
    if (cbase < keff) {
        const f16x8 a0 = *(const f16x8*)&srow[cbase];
        const f16x8 a1 = *(const f16x8*)&srow[cbase + 8];
#pragma unroll
        for (int e = 0; e < 8; e++) { v[e] = (float)a0[e]; v[8 + e] = (float)a1[e]; }
    } else {
#pragma unroll
        for (int e = 0; e < 16; e++) v[e] = 0.f;
    }

    float m = -1e30f;
#pragma unroll
    for (int e = 0; e < 16; e++)
        if (cbase + e < sz) m = fmaxf(m, v[e]);
#pragma unroll
    for (int o = 32; o > 0; o >>= 1) m = fmaxf(m, __shfl_xor(m, o, 64));

    float s = 0.f;
#pragma unroll
    for (int e = 0; e < 16; e++) {
        v[e] = (cbase + e < sz) ? __expf(v[e] - m) : 0.f;
        s += v[e];
    }
#pragma unroll
    for (int o = 32; o > 0; o >>= 1) s += __shfl_xor(s, o, 64);
    const float inv = 1.f / s;

    if (cbase < keff) {
        f16x8 o0, o1;
#pragma unroll
        for (int e = 0; e < 8; e++) {
            o0[e] = (f16)(v[e] * inv);
            o1[e] = (f16)(v[8 + e] * inv);
        }
        *(f16x8*)&srow[cbase] = o0;
        *(f16x8*)&srow[cbase + 8] = o1;
    }
}

__device__ __forceinline__ float gelu_exact(float x) {
    return 0.5f * x * (1.f + erff(x * 0.70710678118654752f));
}

// ---------------------------------------------------------------------------
// gemm256: C[M][N] = A[M][K] * Bt[N][K]^T, 256x256 tile, 8 waves (2Mx4N,
// wave-tile 128x64), BK=32. 2-slot LDS ring (64 KiB) -> 2 blocks/CU;
// per K-step: stage(t+1) -> compute(t) -> vmcnt(0)+barrier. The drain is
// covered by the co-resident block (m97/m114 inter-block overlap).
// Per-slice XCD swizzle (slice nwg % 8 == 0 for all users).
// KT template = compile-time K-tile count (0 = runtime from MASKK).
// LDS bank swizzle: granule g' = g ^ ((row>>1)&3); gload_lds dest linear,
// SOURCE col pre-swizzled (involution). Bank-conflict-free (R4: counter=0).
// MODE 0: f16*alpha. 1: fp32. 2: GELU f16. 3: QKV split (qk | vT^T).
// MASKN: skip block if n0 >= sizes[z]. MASKK: K bounded at round64(sizes[z]).
// ---------------------------------------------------------------------------
#define STAGE256(t)                                                           \
    { const int ts_ = (t); f16* sl = lds + (ts_ & 1) * 16384;                 \
      GLOAD_LDS16(Ap0 + ts_ * 32, sl + tid * 8);                              \
      GLOAD_LDS16(Ap1 + ts_ * 32, sl + (tid + 512) * 8);                      \
      GLOAD_LDS16(Bp0 + ts_ * 32, sl + 8192 + tid * 8);                       \
      GLOAD_LDS16(Bp1 + ts_ * 32, sl + 8192 + (tid + 512) * 8); }

#define COMPUTE256(t)                                                         \
    { const f16* As_ = lds + ((t) & 1) * 16384;                               \
      const f16* Bs_ = As_ + 8192;                                            \
      f16x8 af[8], bf[4];                                                     \
      _Pragma("unroll") for (int i = 0; i < 8; i++)                           \
          af[i] = *(const f16x8*)&As_[(wr + i * 16 + lrow) * 32 + gq];        \
      _Pragma("unroll") for (int j = 0; j < 4; j++)                           \
          bf[j] = *(const f16x8*)&Bs_[(wc + j * 16 + lrow) * 32 + gq];        \
      __builtin_amdgcn_s_setprio(1);                                          \
      _Pragma("unroll") for (int i = 0; i < 8; i++)                           \
      _Pragma("unroll") for (int j = 0; j < 4; j++)                           \
          acc[i][j] = __builtin_amdgcn_mfma_f32_16x16x32_f16(af[i], bf[j], acc[i][j], 0, 0, 0); \
      __builtin_amdgcn_s_setprio(0); }

#define DRAIN256                                                              \
    __builtin_amdgcn_sched_barrier(0);                                        \
    asm volatile("s_waitcnt vmcnt(0)" ::: "memory");                          \
    __builtin_amdgcn_s_barrier();                                             \
    asm volatile("" ::: "memory");

template <int MODE, int MASKN, int MASKK, int KT>
__global__ __launch_bounds__(512, 4) void gemm256(
    const f16* __restrict__ A, int lda, long long strideA,
    const f16* __restrict__ Bt, int ldb, long long strideB,
    void* __restrict__ Cv, int ldc, long long strideC,
    int K, float alpha, const int* __restrict__ sizes, void* __restrict__ Cv2) {
    extern __shared__ __align__(16) f16 lds[];

    const int tid = threadIdx.x;
    const int wave = tid >> 6, lane = tid & 63;
    const int wr = (wave >> 2) * 128, wc = (wave & 3) * 64;
    const int lrow = lane & 15, quad = lane >> 4;
    const int gq = (quad ^ ((lrow >> 1) & 3)) * 8;

    // per-slice XCD swizzle (slice nwg: 768/512/256/16/8 — all % 8 == 0)
    const int gx = gridDim.x;
    const int nwg = gx * (int)gridDim.y;
    const int id = blockIdx.y * gx + blockIdx.x;
    const int wid = (id & 7) * (nwg >> 3) + (id >> 3);
    const int m0 = (wid / gx) * 256;
    const int n0 = (wid % gx) * 256;

    if (MASKN) {
        if (n0 >= sizes[blockIdx.z]) return;
    }
    int NT;
    if constexpr (KT > 0) {
        NT = KT;
    } else {
        int Keff = K;
        if (MASKK) {
            const int ke = (sizes[blockIdx.z] + 63) & ~63;
            if (ke < Keff) Keff = ke;
        }
        NT = Keff >> 5;  // BK=32; NT >= 2 always (Keff >= 64)
    }

    A += (long long)blockIdx.z * strideA;
    Bt += (long long)blockIdx.z * strideB;

    f32x4 acc[8][4];
#pragma unroll
    for (int i = 0; i < 8; i++)
#pragma unroll
        for (int j = 0; j < 4; j++) acc[i][j] = (f32x4){0.f, 0.f, 0.f, 0.f};

    // staging: 2 passes/matrix; slot s -> row=s>>2, granule g=s&3,
    // source col granule = g ^ ((row>>1)&3)  (involution; LDS dest linear)
    const int r0s = tid >> 2, g0s = tid & 3;
    const int r1s = (tid + 512) >> 2;
    const f16* Ap0 = A + (long long)(m0 + r0s) * lda + (g0s ^ ((r0s >> 1) & 3)) * 8;
    const f16* Ap1 = A + (long long)(m0 + r1s) * lda + (g0s ^ ((r1s >> 1) & 3)) * 8;
    const f16* Bp0 = Bt + (long long)(n0 + r0s) * ldb + (g0s ^ ((r0s >> 1) & 3)) * 8;
    const f16* Bp1 = Bt + (long long)(n0 + r1s) * ldb + (g0s ^ ((r1s >> 1) & 3)) * 8;

    STAGE256(0);
    DRAIN256;

    for (int t = 0; t < NT; ++t) {
        if (t + 1 < NT) STAGE256(t + 1);
        COMPUTE256(t);
        DRAIN256;
    }

    // epilogue: C/D layout col=lane&15, row=quad*4+reg
    const int cbase = n0 + wc + lrow;
    if constexpr (MODE == 3) {
        if (n0 >= 1024) {
            // V columns: store transposed into vT[b][d][n] as packed f16x4
            f16* vTp = (f16*)Cv2;
#pragma unroll
            for (int i = 0; i < 8; i++) {
                const int rbase = m0 + wr + i * 16 + quad * 4;
                const int bb = rbase >> 10, nrow = rbase & 1023;
                f16* vb = vTp + (long long)bb * (ND * NN) + nrow;
#pragma unroll
                for (int j = 0; j < 4; j++) {
                    const int col = cbase + j * 16 - 1024;
                    f16x4 pk;
#pragma unroll
                    for (int r = 0; r < 4; r++) pk[r] = (f16)acc[i][j][r];
                    *(f16x4*)&vb[(long long)col * NN] = pk;
                }
            }
            return;
        }
        f16* Ch = (f16*)Cv;
#pragma unroll
        for (int i = 0; i < 8; i++) {
            const int rbase = m0 + wr + i * 16 + quad * 4;
#pragma unroll
            for (int j = 0; j < 4; j++) {
                const int col = cbase + j * 16;
#pragma unroll
                for (int r = 0; r < 4; r++)
                    Ch[(long long)(rbase + r) * ldc + col] = (f16)acc[i][j][r];
            }
        }
        return;
    }
    if constexpr (MODE == 1) {
        float* Cf = (float*)Cv + (long long)blockIdx.z * strideC;
#pragma unroll
        for (int i = 0; i < 8; i++) {
            const int rbase = m0 + wr + i * 16 + quad * 4;
#pragma unroll
            for (int j = 0; j < 4; j++) {
                const int col = cbase + j * 16;
#pragma unroll
                for (int r = 0; r < 4; r++)
                    Cf[(long long)(rbase + r) * ldc + col] = acc[i][j][r];
            }
        }
    } else if constexpr (MODE == 2) {  // GELU -> f16
        f16* Ch = (f16*)Cv + (long long)blockIdx.z * strideC;
#pragma unroll
        for (int i = 0; i < 8; i++) {
            const int rbase = m0 + wr + i * 16 + quad * 4;
#pragma unroll
            for (int j = 0; j < 4; j++) {
                const int col = cbase + j * 16;
#pragma unroll
                for (int r = 0; r < 4; r++)
                    Ch[(long long)(rbase + r) * ldc + col] = (f16)gelu_exact(acc[i][j][r]);
            }
        }
    } else {  // MODE 0: f16 * alpha
        f16* Ch = (f16*)Cv + (long long)blockIdx.z * strideC;
#pragma unroll
        for (int i = 0; i < 8; i++) {
            const int rbase = m0 + wr + i * 16 + quad * 4;
#pragma unroll
            for (int j = 0; j < 4; j++) {
                const int col = cbase + j * 16;
#pragma unroll
                for (int r = 0; r < 4; r++)
                    Ch[(long long)(rbase + r) * ldc + col] = (f16)(acc[i][j][r] * alpha);
            }
        }
    }
}

// ---------------------------------------------------------------------------
// Launch
// ---------------------------------------------------------------------------
extern "C" void kernel_launch(void* const* d_in, const int* in_sizes, int n_in,
                              void* d_out, int out_size, void* d_ws, size_t ws_size,
                              hipStream_t stream) {
    const float* x     = (const float*)d_in[0];
    const int*   sizes = (const int*)d_in[1];
    const float* g1    = (const float*)d_in[2];
    const float* wqkv  = (const float*)d_in[3];
    const float* g2    = (const float*)d_in[4];
    const float* wfc   = (const float*)d_in[5];
    const float* wproj = (const float*)d_in[6];
    float* out = (float*)d_out;
    char* ws = (char*)d_ws;

    // ---- d_ws layout (floor: 100 MiB, proven available) ----
    f16* wqkvT  = (f16*)(ws + (0ull << 20));    // 1.5 MiB  [1536][512]
    f16* wfcT   = (f16*)(ws + (2ull << 20));    // 0.5 MiB
    f16* wprojT = (f16*)(ws + (3ull << 20));    // 0.5 MiB
    f16* qk     = (f16*)(ws + (4ull << 20));    // 64 MiB [b][n][1024] (q|k)
    f16* vT     = (f16*)(ws + (68ull << 20));   // 32 MiB [b][d][n]
    f16* y      = (f16*)(ws + (4ull << 20));    // 32 MiB (qk lo, dead after scores)
    f16* ln2o   = (f16*)(ws + (36ull << 20));   // 32 MiB (qk hi, dead after scores)
    f16* gelub  = (f16*)(ws + (68ull << 20));   // 32 MiB (vT, dead after attnV)

    // ---- d_out scratch ----
    f16* h      = (f16*)d_out;   // 32 MiB, dead after QKV
    f16* scores = (f16*)d_out;   // 64 MiB (all 32 batches; h dead)

    const long long sstr = (long long)NN * NN;     // score batch stride
    const long long qstr = (long long)NN * 1024;   // qk batch stride
    const long long vstr = (long long)ND * NN;     // vT batch stride
    const long long ystr = (long long)NN * ND;     // y batch stride

    const size_t LDSB = 65536;  // 64 KiB dynamic LDS -> 2 blocks/CU

    // prep: weights -> f16 transposed  +  LN1 (x -> h), one launch
    prep_fused<<<2304 + NB * NN / 4, 256, 0, stream>>>(
        wqkv, wqkvT, wfc, wfcT, wproj, wprojT, x, g1, h);

    // QKV: q,k -> qk[b][n][1024]; v -> vT[b][d][n] (fused transpose)
    gemm256<3, 0, 0, 16><<<dim3(6, 128, 1), 512, LDSB, stream>>>(
        h, 512, 0, wqkvT, 512, 0, qk, 1024, 0, 512, 1.0f, nullptr, vT);

    // scores (f16) = q @ k^T / sqrt(D); skip fully-masked 256-col blocks
    gemm256<0, 1, 0, 16><<<dim3(4, 4, 32), 512, LDSB, stream>>>(
        qk, 1024, qstr, qk + 512, 1024, qstr,
        scores, NN, sstr, 512, 0.044194173824159216f, sizes, nullptr);

    // masked softmax in place (wave per row), zero-fill to round64(sz)
    softmax_wave<<<dim3(NN / 4, NB), 256, 0, stream>>>(scores, sizes);

    // y = attn @ v; K bounded at round64(size)
    gemm256<0, 0, 1, 0><<<dim3(2, 4, 32), 512, LDSB, stream>>>(
        scores, NN, sstr, vT, NN, vstr,
        y, ND, ystr, NN, 1.0f, sizes, nullptr);

    // LN2: y -> ln2o (qk hi region, dead)
    ln_wave_h<<<NB * NN / 4, 256, 0, stream>>>(y, g2, ln2o);

    // FC + exact GELU: ln2o -> gelub (vT region, dead)
    gemm256<2, 0, 0, 16><<<dim3(2, 128, 1), 512, LDSB, stream>>>(
        ln2o, 512, 0, wfcT, 512, 0, gelub, 512, 0, 512, 1.0f, nullptr, nullptr);

    // proj -> out (fp32, overwrites all of d_out; scores dead)
    gemm256<1, 0, 0, 16><<<dim3(2, 128, 1), 512, LDSB, stream>>>(
        gelub, 512, 0, wprojT, 512, 0, out, 512, 0, 512, 1.0f, nullptr, nullptr);
}